// Round 3
// baseline (280.416 us; speedup 1.0000x reference)
//
#include <hip/hip_runtime.h>
#include <hip/hip_bf16.h>

typedef __attribute__((ext_vector_type(8))) short bf16x8;
typedef __attribute__((ext_vector_type(4))) float f32x4;
typedef __attribute__((ext_vector_type(16))) float f32x16;

#define BATCH 32
#define SEQ   2048
#define LOG2E 1.44269504088896340736f
#define QSCALE (0.125f * LOG2E)
#define NEGL  (-1000000.0f * LOG2E)

__device__ __forceinline__ unsigned int pk2(float lo, float hi) {
    __hip_bfloat162 h2 = __float22bfloat162_rn(make_float2(lo, hi));  // v_cvt_pk_bf16_f32
    return *reinterpret_cast<unsigned int*>(&h2);
}

// v_permlane32_swap_b32: a[32:63] <-> b[0:31].
__device__ __forceinline__ void plswap(unsigned int& a, unsigned int& b) {
    asm volatile("v_permlane32_swap_b32 %0, %1" : "+v"(a), "+v"(b));
}

// ---- round-14: SINGLE FUSED KERNEL. Round-2 post-mortem: total-attn ~= 80us
// constant across rounds -> prepkv + extra launch + 64MB workspace round-trip
// was the bigger half. Round-13 post-mortem: per-lane fragment loads shatter
// coalescing (32 lines/instr) -> keep LDS staging, but stage fp32->bf16
// IN-KERNEL: coalesced reg loads (T14 issue-early / convert-late), pk2, swizzled
// ds_write. Compute core = verified round-1 structure (32x32 MFMA, in-reg P^T,
// 1 barrier/tile via write(kt)->barrier->compute(kt) chain; raw s_barrier +
// lgkmcnt(0) only -> in-flight global loads NOT drained at barrier).
// Per-block wave-0 rank-sort of valid_lens (meta kernel + workspace gone). ----
__global__ __launch_bounds__(256, 4)
void attn_fwd(const float* __restrict__ Qp, const float* __restrict__ Kp,
              const float* __restrict__ Vp, const int* __restrict__ VL,
              float* __restrict__ Out) {
    constexpr int S = SEQ;
    __shared__ short bK2[2 * 4096];   // [buf][row 64][64 bf16], XOR-swizzled chunks
    __shared__ short bV2[2 * 4096];   // [buf][d 64][64 keys packed pairs], swizzled
    __shared__ int sv[BATCH];
    __shared__ int sb[2];             // this block's (vl, batch)

    const int tid  = threadIdx.x;
    const int wave = tid >> 6, lane = tid & 63;
    const int r31 = lane & 31, hi = lane >> 5;
    const int l7  = lane & 7;
    const int qh = wave >> 1, kh = wave & 1;   // q-half, key-half

    // snake remap: CU c gets slots {k,15-k,16+k,31-k} -> balanced tile sums
    const int g  = blockIdx.x >> 8;
    const int k8 = (blockIdx.x >> 5) & 7;
    const int qt = blockIdx.x & 31;
    const int slot = (g << 3) + ((g & 1) ? 7 - k8 : k8);

    // ---- per-block meta: rank-sort valid_lens in wave 0 (LPT order) ----
    if (tid < 64) {
        int odd = (tid < 16) ? VL[2 * tid + 1] : 0;
        const bool is64 = (__ballot(odd != 0) == 0ULL);   // int64 lens (hi words 0)
        int x = 0;
        if (tid < BATCH) {
            x = is64 ? VL[2 * tid] : VL[tid];
            x = x < 0 ? 0 : (x > SEQ ? SEQ : x);
            sv[tid] = x;
        }
        asm volatile("s_waitcnt lgkmcnt(0)" ::: "memory");
        if (tid < BATCH) {
            int rank = 0;
            for (int j = 0; j < BATCH; ++j) {
                const int y = sv[j];
                rank += (y > x) || (y == x && j < tid);
            }
            if (rank == slot) { sb[0] = x; sb[1] = tid; }
        }
    }
    __syncthreads();
    const int vl = sb[0], batch = sb[1];
    const int ntiles = (vl + 63) >> 6;

    const float* Kf = Kp + (size_t)batch * S * 64;
    const float* Vf = Vp + (size_t)batch * S * 64;

    // ---- staging geometry (constant per thread) ----
    // K: thread h-slice covers row=c>>4, 4 floats at col (c&15)*4
    int kRow[4], kByte[4];
    const float* pKg[4];
    #pragma unroll
    for (int h = 0; h < 4; ++h) {
        const int c = tid + h * 256;
        const int row = c >> 4, q8 = c & 15;
        kRow[h] = row;
        kByte[h] = row * 128 + ((((q8 >> 1) ^ (row & 7)) << 4)) + ((q8 & 1) << 3);
        pKg[h] = Kf + row * 64 + q8 * 4;
    }
    // V: thread h-slice covers key-pair kp, 4 depths d4*4..+3 of both keys
    int vByte[2][4];
    const float* pVa[2];
    #pragma unroll
    for (int h = 0; h < 2; ++h) {
        const int u = tid + h * 256;
        const int d4 = (u & 3) + ((u >> 7) << 2);
        const int kp = (u >> 2) & 31;
        pVa[h] = Vf + (2 * kp) * 64 + d4 * 4;
        #pragma unroll
        for (int j = 0; j < 4; ++j) {
            const int d = d4 * 4 + j;
            vByte[h][j] = d * 128 + (((kp >> 2) ^ (d & 7)) << 4) + ((kp & 3) << 2);
        }
    }

    // ---- Q B-fragments: lane holds Q[qh*32+r31][kf*16+hi*8+j], scale folded ----
    bf16x8 qf[4];
    {
        const float* qb = Qp + ((size_t)batch * S + qt * 64 + qh * 32 + r31) * 64 + hi * 8;
        #pragma unroll
        for (int kf = 0; kf < 4; ++kf) {
            f32x4 a = *(const f32x4*)(qb + kf * 16);
            f32x4 c = *(const f32x4*)(qb + kf * 16 + 4);
            union { bf16x8 v; unsigned int u[4]; } qq;
            qq.u[0] = pk2(a[0] * QSCALE, a[1] * QSCALE);
            qq.u[1] = pk2(a[2] * QSCALE, a[3] * QSCALE);
            qq.u[2] = pk2(c[0] * QSCALE, c[1] * QSCALE);
            qq.u[3] = pk2(c[2] * QSCALE, c[3] * QSCALE);
            qf[kf] = qq.v;
        }
    }

    f32x16 o0, o1;
    #pragma unroll
    for (int r = 0; r < 16; ++r) { o0[r] = 0.f; o1[r] = 0.f; }
    float lpart = 0.f;

    // ---- preload + convert tile 0 ----
    unsigned int kw[8], vw[8];
    if (ntiles > 0) {
        f32x4 ka[4], va[2], vc[2];
        #pragma unroll
        for (int h = 0; h < 4; ++h) ka[h] = *(const f32x4*)(pKg[h]);
        #pragma unroll
        for (int h = 0; h < 2; ++h) {
            va[h] = *(const f32x4*)(pVa[h]);
            vc[h] = *(const f32x4*)(pVa[h] + 64);
        }
        #pragma unroll
        for (int h = 0; h < 4; ++h) {
            kw[2 * h]     = pk2(ka[h][0], ka[h][1]);
            kw[2 * h + 1] = pk2(ka[h][2], ka[h][3]);
        }
        #pragma unroll
        for (int h = 0; h < 2; ++h)
            #pragma unroll
            for (int j = 0; j < 4; ++j) vw[4 * h + j] = pk2(va[h][j], vc[h][j]);
    }

    for (int kt = 0; kt < ntiles; ++kt) {
        // ---- ds_write tile kt into buf[kt&1] (swizzled; safe via barrier chain) ----
        char* cK = (char*)bK2 + (kt & 1) * 8192;
        char* cV = (char*)bV2 + (kt & 1) * 8192;
        #pragma unroll
        for (int h = 0; h < 4; ++h) {
            uint2 w2; w2.x = kw[2 * h]; w2.y = kw[2 * h + 1];
            *(uint2*)(cK + kByte[h]) = w2;
        }
        #pragma unroll
        for (int h = 0; h < 2; ++h)
            #pragma unroll
            for (int j = 0; j < 4; ++j)
                *(unsigned int*)(cV + vByte[h][j]) = vw[4 * h + j];

        // ---- issue fp32 loads for tile kt+1 (vmcnt waited after compute) ----
        f32x4 ka[4], va[2], vc[2];
        const bool more = (kt + 1 < ntiles);
        if (more) {
            const int off = (kt + 1) * 4096;   // floats per 64x64 tile
            #pragma unroll
            for (int h = 0; h < 4; ++h) ka[h] = *(const f32x4*)(pKg[h] + off);
            #pragma unroll
            for (int h = 0; h < 2; ++h) {
                va[h] = *(const f32x4*)(pVa[h] + off);
                vc[h] = *(const f32x4*)(pVa[h] + off + 64);
            }
        }

        // writes visible to all waves; do NOT drain vmcnt (prefetch stays in flight)
        asm volatile("s_waitcnt lgkmcnt(0)\n\ts_barrier" ::: "memory");

        // ---- compute (guard: this wave's key-half has work in this tile) ----
        if (kt * 64 + kh * 32 < vl) {
            const int krow = kh * 32 + r31;
            f32x16 st;
            #pragma unroll
            for (int r = 0; r < 16; ++r) st[r] = 0.f;
            __builtin_amdgcn_s_setprio(1);
            #pragma unroll
            for (int kf = 0; kf < 4; ++kf) {
                bf16x8 kfr = *(const bf16x8*)(cK + krow * 128 +
                                              (((kf * 2 + hi) ^ l7) << 4));
                st = __builtin_amdgcn_mfma_f32_32x32x16_bf16(kfr, qf[kf], st, 0, 0, 0);
            }
            __builtin_amdgcn_s_setprio(0);

            // mask the last partial 32-key half (wave-uniform branch)
            const int rem = vl - (kt * 64 + kh * 32);
            if (rem < 32) {
                #pragma unroll
                for (int r = 0; r < 16; ++r) {
                    const int kl = 4 * hi + (r & 3) + 8 * (r >> 2);
                    st[r] = (kl < rem) ? st[r] : NEGL;
                }
            }

            // p = exp2(s') (log2 domain, no max subtraction; masked -> exactly 0)
            #pragma unroll
            for (int r = 0; r < 16; ++r) st[r] = exp2f(st[r]);
            {
                const float a0 = (st[0] + st[1]) + (st[2] + st[3]);
                const float a1 = (st[4] + st[5]) + (st[6] + st[7]);
                const float a2 = (st[8] + st[9]) + (st[10] + st[11]);
                const float a3 = (st[12] + st[13]) + (st[14] + st[15]);
                lpart += (a0 + a1) + (a2 + a3);
            }

            // in-register P^T -> PV B-fragments (T12)
            union { bf16x8 v; unsigned int u[4]; } pf0, pf1;
            {
                unsigned int x0 = pk2(st[0], st[1]),   y0 = pk2(st[4], st[5]);
                unsigned int x1 = pk2(st[2], st[3]),   y1 = pk2(st[6], st[7]);
                plswap(x0, y0); plswap(x1, y1);
                pf0.u[0] = x0; pf0.u[1] = x1; pf0.u[2] = y0; pf0.u[3] = y1;
                unsigned int x2 = pk2(st[8], st[9]),   y2 = pk2(st[12], st[13]);
                unsigned int x3 = pk2(st[10], st[11]), y3 = pk2(st[14], st[15]);
                plswap(x2, y2); plswap(x3, y3);
                pf1.u[0] = x2; pf1.u[1] = x3; pf1.u[2] = y2; pf1.u[3] = y3;
            }

            // O^T += V^T P^T
            __builtin_amdgcn_s_setprio(1);
            {
                bf16x8 vf0 = *(const bf16x8*)(cV + r31 * 128 + (((kh * 4 + hi) ^ l7) << 4));
                o0 = __builtin_amdgcn_mfma_f32_32x32x16_bf16(vf0, pf0.v, o0, 0, 0, 0);
                bf16x8 vf1 = *(const bf16x8*)(cV + r31 * 128 + (((kh * 4 + 2 + hi) ^ l7) << 4));
                o0 = __builtin_amdgcn_mfma_f32_32x32x16_bf16(vf1, pf1.v, o0, 0, 0, 0);
                bf16x8 vf2 = *(const bf16x8*)(cV + (32 + r31) * 128 + (((kh * 4 + hi) ^ l7) << 4));
                o1 = __builtin_amdgcn_mfma_f32_32x32x16_bf16(vf2, pf0.v, o1, 0, 0, 0);
                bf16x8 vf3 = *(const bf16x8*)(cV + (32 + r31) * 128 + (((kh * 4 + 2 + hi) ^ l7) << 4));
                o1 = __builtin_amdgcn_mfma_f32_32x32x16_bf16(vf3, pf1.v, o1, 0, 0, 0);
            }
            __builtin_amdgcn_s_setprio(0);
        }

        // ---- convert tile kt+1 fp32 -> bf16 words (vmcnt waits land HERE,
        //      after the long compute phase, not at the barrier) ----
        if (more) {
            #pragma unroll
            for (int h = 0; h < 4; ++h) {
                kw[2 * h]     = pk2(ka[h][0], ka[h][1]);
                kw[2 * h + 1] = pk2(ka[h][2], ka[h][3]);
            }
            #pragma unroll
            for (int h = 0; h < 2; ++h)
                #pragma unroll
                for (int j = 0; j < 4; ++j) vw[4 * h + j] = pk2(va[h][j], vc[h][j]);
        }
    }

    // per-(q, key-half) l: lanes l and l+32 hold complementary row sets
    float lw = lpart + __shfl_xor(lpart, 32);

    // cross-wave merge (kh=0 += kh=1): pure sums, once per block
    __syncthreads();                          // all waves done reading K/V tiles
    float* mrg = (float*)bK2;                 // 4096 floats = 16 KB
    float* lm  = (float*)bV2;
    if (kh == 1) {
        #pragma unroll
        for (int r = 0; r < 16; ++r) mrg[qh * 2048 + r * 64 + lane] = o0[r];
        #pragma unroll
        for (int r = 0; r < 16; ++r) mrg[qh * 2048 + (16 + r) * 64 + lane] = o1[r];
        lm[qh * 64 + lane] = lw;
    }
    __syncthreads();
    if (kh == 0) {
        #pragma unroll
        for (int r = 0; r < 16; ++r) o0[r] += mrg[qh * 2048 + r * 64 + lane];
        #pragma unroll
        for (int r = 0; r < 16; ++r) o1[r] += mrg[qh * 2048 + (16 + r) * 64 + lane];
        lw += lm[qh * 64 + lane];
        const float inv = (lw > 0.f) ? 1.0f / lw : 0.f;
        const size_t orow = ((size_t)batch * S + qt * 64 + qh * 32 + r31) * 64;
        #pragma unroll
        for (int g4 = 0; g4 < 4; ++g4) {
            f32x4 w;
            #pragma unroll
            for (int j = 0; j < 4; ++j) w[j] = o0[g4 * 4 + j] * inv;
            *(f32x4*)(Out + orow + g4 * 8 + hi * 4) = w;
        }
        #pragma unroll
        for (int g4 = 0; g4 < 4; ++g4) {
            f32x4 w;
            #pragma unroll
            for (int j = 0; j < 4; ++j) w[j] = o1[g4 * 4 + j] * inv;
            *(f32x4*)(Out + orow + 32 + g4 * 8 + hi * 4) = w;
        }
    }
}

extern "C" void kernel_launch(void* const* d_in, const int* in_sizes, int n_in,
                              void* d_out, int out_size, void* d_ws, size_t ws_size,
                              hipStream_t stream) {
    const float* Q  = (const float*)d_in[0];
    const float* K  = (const float*)d_in[1];
    const float* V  = (const float*)d_in[2];
    const int*   VL = (const int*)d_in[3];
    attn_fwd<<<dim3(BATCH * 32), dim3(256), 0, stream>>>(Q, K, V, VL, (float*)d_out);
}

// Round 4
// 126.249 us; speedup vs baseline: 2.2211x; 2.2211x over previous
//
#include <hip/hip_runtime.h>
#include <hip/hip_bf16.h>

typedef __attribute__((ext_vector_type(8))) short bf16x8;
typedef __attribute__((ext_vector_type(4))) float f32x4;
typedef __attribute__((ext_vector_type(16))) float f32x16;

#define BATCH 32
#define SEQ   2048
#define PSTR  20    // fallback kernel only
#define KSTR  72    // fallback kernel only
#define VSTR  36    // fallback + prepkv staging
#define LOG2E 1.44269504088896340736f
#define QSCALE (0.125f * LOG2E)
#define NEGL  (-1000000.0f * LOG2E)

__device__ __forceinline__ unsigned int pk2(float lo, float hi) {
    __hip_bfloat162 h2 = __float22bfloat162_rn(make_float2(lo, hi));  // v_cvt_pk_bf16_f32
    return *reinterpret_cast<unsigned int*>(&h2);
}

__device__ __forceinline__ void dma16(const short* g, short* l) {
    __builtin_amdgcn_global_load_lds((const __attribute__((address_space(1))) void*)g,
                                     (__attribute__((address_space(3))) void*)l, 16, 0, 0);
}

// v_permlane32_swap_b32: a[32:63] <-> b[0:31].
__device__ __forceinline__ void plswap(unsigned int& a, unsigned int& b) {
    asm volatile("v_permlane32_swap_b32 %0, %1" : "+v"(a), "+v"(b));
}

// standalone prep (fallback path only)
__global__ void prep_vl(const int* __restrict__ VL, int* __restrict__ meta) {
    __shared__ int sv[BATCH];
    const int t = threadIdx.x;
    int odd = (t < 16) ? VL[2 * t + 1] : 0;
    const bool is64 = (__ballot(odd != 0) == 0ULL);
    if (t < BATCH) {
        int x = is64 ? VL[2 * t] : VL[t];
        x = x < 0 ? 0 : (x > SEQ ? SEQ : x);
        sv[t] = x;
    }
    __syncthreads();
    if (t < BATCH) {
        const int x = sv[t];
        int rank = 0;
        for (int j = 0; j < BATCH; ++j) {
            const int y = sv[j];
            rank += (y > x) || (y == x && j < t);
        }
        meta[rank] = x;
        meta[BATCH + rank] = t;
    }
}

// K fp32->bf16 row-major [b][key][d]; V fp32->bf16 TILE-MAJOR transposed
// Vt[b][kt][d][64 keys] (packed key-pairs). Round-14: tiles entirely beyond
// vl[b] are SKIPPED (attn never stages them; saves ~45 MB of the 96 MB).
// Block BATCH*32 does the meta rank-sort wave-synchronously.
__global__ __launch_bounds__(256) void prepkv(const float* __restrict__ Kp,
                                              const float* __restrict__ Vp,
                                              const int* __restrict__ VL,
                                              short* __restrict__ Kb,
                                              short* __restrict__ Vt,
                                              int* __restrict__ meta) {
    __shared__ unsigned int l[64 * VSTR];
    __shared__ int sv[BATCH];
    __shared__ int svl;
    const int tid = threadIdx.x;
    if (blockIdx.x == BATCH * 32) {
        if (tid < 64) {
            int odd = (tid < 16) ? VL[2 * tid + 1] : 0;
            const bool is64 = (__ballot(odd != 0) == 0ULL);   // lens>=1
            if (tid < BATCH) {
                int x = is64 ? VL[2 * tid] : VL[tid];
                x = x < 0 ? 0 : (x > SEQ ? SEQ : x);
                sv[tid] = x;
            }
            asm volatile("s_waitcnt lgkmcnt(0)" ::: "memory");
            if (tid < BATCH) {
                const int x = sv[tid];
                int rank = 0;
                for (int j = 0; j < BATCH; ++j) {
                    const int y = sv[j];
                    rank += (y > x) || (y == x && j < tid);
                }
                meta[rank] = x;
                meta[BATCH + rank] = tid;
            }
        }
        return;
    }
    const int b = blockIdx.x >> 5, kt = blockIdx.x & 31, kb = kt * 64;
    // per-block vl: skip tiles attn never reads (kt*64 >= vl)
    if (tid < 64) {
        int odd = (tid < 16) ? VL[2 * tid + 1] : 0;
        const bool is64 = (__ballot(odd != 0) == 0ULL);
        if (tid == 0) {
            int x = is64 ? VL[2 * b] : VL[b];
            x = x < 0 ? 0 : (x > SEQ ? SEQ : x);
            svl = x;
        }
    }
    __syncthreads();
    if (kb >= svl) return;   // block-uniform exit
    const float* Kv = Kp + ((size_t)b * SEQ + kb) * 64;
    const float* Vb = Vp + ((size_t)b * SEQ + kb) * 64;
    #pragma unroll
    for (int h = 0; h < 4; ++h) {
        const int c = tid + h * 256;
        const int row = c >> 4, col = (c & 15) * 4;
        f32x4 x = *(const f32x4*)(Kv + row * 64 + col);
        unsigned int* dst = (unsigned int*)(Kb + ((size_t)b * SEQ + kb + row) * 64 + col);
        dst[0] = pk2(x[0], x[1]); dst[1] = pk2(x[2], x[3]);
    }
    #pragma unroll
    for (int h = 0; h < 2; ++h) {
        const int u = tid + h * 256;
        const int d4 = (u & 3) + ((u >> 7) << 2);
        const int kp = (u >> 2) & 31;
        f32x4 a = *(const f32x4*)(Vb + (2 * kp) * 64 + d4 * 4);
        f32x4 c = *(const f32x4*)(Vb + (2 * kp + 1) * 64 + d4 * 4);
        #pragma unroll
        for (int j = 0; j < 4; ++j)
            l[(d4 * 4 + j) * VSTR + kp] = pk2(a[j], c[j]);
    }
    __syncthreads();
    // tile-major write: uint index ((b*32+kt)*64 + d)*32 + kp -> contiguous 8 KB/block
    const int d = tid >> 2, cg = tid & 3;
    unsigned int w[8];
    #pragma unroll
    for (int j = 0; j < 8; ++j) w[j] = l[d * VSTR + cg * 8 + j];
    unsigned int* dst = (unsigned int*)Vt + ((size_t)(b * 32 + kt) * 64 + d) * 32 + cg * 8;
    #pragma unroll
    for (int j = 0; j < 8; ++j) dst[j] = w[j];
}

// ---- main: round-14 = verified round-2 structure (48-50us: 32x32 MFMA,
// in-reg P^T via cvt_pk+permlane, DMA double-buffer, 1 barrier/tile) plus:
// (a) persistent zero-acc zv (kills 16 v_mov/tile; VALUBusy was 45% = top pipe),
// (b) tile loop unrolled x2 -> compile-time buffer parity, hoisted LDS addrs,
// (c) s_setprio(1) around both MFMA clusters (m191 attn regime: +4-7%).
// Round-3 post-mortem pinned: fused fp32 path = 346MB L2-miss traffic, keep
// the bf16 workspace; ~60us of bench total is fixed harness overhead. ----
__global__ __launch_bounds__(256, 4)
void attn_fwd(const float* __restrict__ Qp, const short* __restrict__ Kb,
              const short* __restrict__ Vt, const int* __restrict__ meta,
              float* __restrict__ Out) {
    constexpr int S = SEQ;
    __shared__ short bK2[2 * 64 * 64];
    __shared__ short bV2[2 * 64 * 64];

    const int tid  = threadIdx.x;
    const int wave = tid >> 6, lane = tid & 63;
    const int r31 = lane & 31, hi = lane >> 5;
    const int l7  = lane & 7;
    const int qh = wave >> 1, kh = wave & 1;   // q-half, key-half

    // snake remap: CU c gets slots {k,15-k,16+k,31-k} -> balanced tile sums
    const int g  = blockIdx.x >> 8;
    const int k8 = (blockIdx.x >> 5) & 7;
    const int qt = blockIdx.x & 31;
    const int slot = (g << 3) + ((g & 1) ? 7 - k8 : k8);

    const int vl = meta[slot], batch = meta[BATCH + slot];
    const int ntiles = (vl + 63) >> 6;

    const short* Kbb = Kb + (size_t)batch * S * 64;
    const short* Vtb = Vt + (size_t)batch * 32 * 4096;   // tile-major: 4096 shorts/tile

    // staging: source-side XOR swizzle (linear LDS dest + pre-swizzled global
    // source + swizzled read). LDS[row][slot s] = G[row][s ^ (row&7)].
    const int r8 = lane >> 3, s8 = lane & 7, csw = s8 ^ r8;
    const short* gK0 = Kbb + (wave * 16 + r8) * 64 + csw * 8;
    const short* gV0 = Vtb + (wave * 16 + r8) * 64 + csw * 8;
    short* lK0 = &bK2[wave * 16 * 64];
    short* lV0 = &bV2[wave * 16 * 64];

    // Q B-fragments: lane holds Q[qh*32+r31][kf*16+hi*8+j], scale folded
    // (scores exit MFMA in log2 domain)
    bf16x8 qf[4];
    {
        const float* qb = Qp + ((size_t)batch * S + qt * 64 + qh * 32 + r31) * 64 + hi * 8;
        #pragma unroll
        for (int kf = 0; kf < 4; ++kf) {
            f32x4 a = *(const f32x4*)(qb + kf * 16);
            f32x4 c = *(const f32x4*)(qb + kf * 16 + 4);
            union { bf16x8 v; unsigned int u[4]; } qq;
            qq.u[0] = pk2(a[0] * QSCALE, a[1] * QSCALE);
            qq.u[1] = pk2(a[2] * QSCALE, a[3] * QSCALE);
            qq.u[2] = pk2(c[0] * QSCALE, c[1] * QSCALE);
            qq.u[3] = pk2(c[2] * QSCALE, c[3] * QSCALE);
            qf[kf] = qq.v;
        }
    }

    f32x16 o0, o1, zv;
    #pragma unroll
    for (int r = 0; r < 16; ++r) { o0[r] = 0.f; o1[r] = 0.f; zv[r] = 0.f; }
    float lpart = 0.f;                      // per-lane partial Σp; merged ONCE at end
    const int krow = kh * 32 + r31;

    if (ntiles > 0) {
        dma16(gK0,       lK0);
        dma16(gK0 + 512, lK0 + 512);
        dma16(gV0,       lV0);
        dma16(gV0 + 512, lV0 + 512);
    }

    // ---- one K/V tile: BUF is compile-time (0/1) -> all LDS addrs hoisted ----
#define ATTN_TILE(KT, BUF)                                                       \
    {                                                                            \
        __syncthreads(); /* drains own DMA for tile KT; orders buf reuse */      \
        if ((KT) + 1 < ntiles) {                                                 \
            const int ko = ((KT) + 1) * 4096;                                    \
            dma16(gK0 + ko,       lK0 + ((BUF) ^ 1) * 4096);                     \
            dma16(gK0 + ko + 512, lK0 + ((BUF) ^ 1) * 4096 + 512);               \
            dma16(gV0 + ko,       lV0 + ((BUF) ^ 1) * 4096);                     \
            dma16(gV0 + ko + 512, lV0 + ((BUF) ^ 1) * 4096 + 512);               \
        }                                                                        \
        if ((KT) * 64 + kh * 32 < vl) {                                          \
            const char* bK = (const char*)&bK2[(BUF) * 4096];                    \
            const char* bV = (const char*)&bV2[(BUF) * 4096];                    \
            f32x16 st;                                                           \
            __builtin_amdgcn_s_setprio(1);                                       \
            {                                                                    \
                bf16x8 k0 = *(const bf16x8*)(bK + krow * 128 + (((0 + hi) ^ l7) << 4)); \
                bf16x8 k1 = *(const bf16x8*)(bK + krow * 128 + (((2 + hi) ^ l7) << 4)); \
                bf16x8 k2 = *(const bf16x8*)(bK + krow * 128 + (((4 + hi) ^ l7) << 4)); \
                bf16x8 k3 = *(const bf16x8*)(bK + krow * 128 + (((6 + hi) ^ l7) << 4)); \
                st = __builtin_amdgcn_mfma_f32_32x32x16_bf16(k0, qf[0], zv, 0, 0, 0); \
                st = __builtin_amdgcn_mfma_f32_32x32x16_bf16(k1, qf[1], st, 0, 0, 0); \
                st = __builtin_amdgcn_mfma_f32_32x32x16_bf16(k2, qf[2], st, 0, 0, 0); \
                st = __builtin_amdgcn_mfma_f32_32x32x16_bf16(k3, qf[3], st, 0, 0, 0); \
            }                                                                    \
            __builtin_amdgcn_s_setprio(0);                                       \
            const int rem = vl - ((KT) * 64 + kh * 32);                          \
            if (rem < 32) {                                                      \
                _Pragma("unroll")                                                \
                for (int r = 0; r < 16; ++r) {                                   \
                    const int kl = 4 * hi + (r & 3) + 8 * (r >> 2);              \
                    st[r] = (kl < rem) ? st[r] : NEGL;                           \
                }                                                                \
            }                                                                    \
            _Pragma("unroll")                                                    \
            for (int r = 0; r < 16; ++r) st[r] = exp2f(st[r]);                   \
            {                                                                    \
                const float a0 = (st[0] + st[1]) + (st[2] + st[3]);              \
                const float a1 = (st[4] + st[5]) + (st[6] + st[7]);              \
                const float a2 = (st[8] + st[9]) + (st[10] + st[11]);            \
                const float a3 = (st[12] + st[13]) + (st[14] + st[15]);          \
                lpart += (a0 + a1) + (a2 + a3);                                  \
            }                                                                    \
            union { bf16x8 v; unsigned int u[4]; } pf0, pf1;                     \
            {                                                                    \
                unsigned int x0 = pk2(st[0], st[1]),   y0 = pk2(st[4], st[5]);   \
                unsigned int x1 = pk2(st[2], st[3]),   y1 = pk2(st[6], st[7]);   \
                plswap(x0, y0); plswap(x1, y1);                                  \
                pf0.u[0] = x0; pf0.u[1] = x1; pf0.u[2] = y0; pf0.u[3] = y1;      \
                unsigned int x2 = pk2(st[8], st[9]),   y2 = pk2(st[12], st[13]); \
                unsigned int x3 = pk2(st[10], st[11]), y3 = pk2(st[14], st[15]); \
                plswap(x2, y2); plswap(x3, y3);                                  \
                pf1.u[0] = x2; pf1.u[1] = x3; pf1.u[2] = y2; pf1.u[3] = y3;      \
            }                                                                    \
            __builtin_amdgcn_s_setprio(1);                                       \
            {                                                                    \
                bf16x8 vf0 = *(const bf16x8*)(bV + r31 * 128 + (((kh * 4 + hi) ^ l7) << 4)); \
                o0 = __builtin_amdgcn_mfma_f32_32x32x16_bf16(vf0, pf0.v, o0, 0, 0, 0); \
                bf16x8 vf1 = *(const bf16x8*)(bV + r31 * 128 + (((kh * 4 + 2 + hi) ^ l7) << 4)); \
                o0 = __builtin_amdgcn_mfma_f32_32x32x16_bf16(vf1, pf1.v, o0, 0, 0, 0); \
                bf16x8 vf2 = *(const bf16x8*)(bV + (32 + r31) * 128 + (((kh * 4 + hi) ^ l7) << 4)); \
                o1 = __builtin_amdgcn_mfma_f32_32x32x16_bf16(vf2, pf0.v, o1, 0, 0, 0); \
                bf16x8 vf3 = *(const bf16x8*)(bV + (32 + r31) * 128 + (((kh * 4 + 2 + hi) ^ l7) << 4)); \
                o1 = __builtin_amdgcn_mfma_f32_32x32x16_bf16(vf3, pf1.v, o1, 0, 0, 0); \
            }                                                                    \
            __builtin_amdgcn_s_setprio(0);                                       \
        }                                                                        \
    }

    for (int kt = 0; kt < ntiles; kt += 2) {
        ATTN_TILE(kt, 0);
        if (kt + 1 < ntiles) ATTN_TILE(kt + 1, 1);
    }
#undef ATTN_TILE

    // per-(q, key-half) l: lanes l and l+32 hold complementary row sets
    float lw = lpart + __shfl_xor(lpart, 32);

    // cross-wave merge (kh=0 += kh=1): pure sums, once per block
    __syncthreads();                          // all waves done reading K/V tiles
    float* mrg = (float*)bK2;                 // 4096 floats = 16 KB
    float* lm  = (float*)bV2;
    if (kh == 1) {
        #pragma unroll
        for (int r = 0; r < 16; ++r) mrg[qh * 2048 + r * 64 + lane] = o0[r];
        #pragma unroll
        for (int r = 0; r < 16; ++r) mrg[qh * 2048 + (16 + r) * 64 + lane] = o1[r];
        lm[qh * 64 + lane] = lw;
    }
    __syncthreads();
    if (kh == 0) {
        #pragma unroll
        for (int r = 0; r < 16; ++r) o0[r] += mrg[qh * 2048 + r * 64 + lane];
        #pragma unroll
        for (int r = 0; r < 16; ++r) o1[r] += mrg[qh * 2048 + (16 + r) * 64 + lane];
        lw += lm[qh * 64 + lane];
        const float inv = (lw > 0.f) ? 1.0f / lw : 0.f;
        const size_t orow = ((size_t)batch * S + qt * 64 + qh * 32 + r31) * 64;
        #pragma unroll
        for (int g4 = 0; g4 < 4; ++g4) {
            f32x4 w;
            #pragma unroll
            for (int j = 0; j < 4; ++j) w[j] = o0[g4 * 4 + j] * inv;
            *(f32x4*)(Out + orow + g4 * 8 + hi * 4) = w;
        }
        #pragma unroll
        for (int g4 = 0; g4 < 4; ++g4) {
            f32x4 w;
            #pragma unroll
            for (int j = 0; j < 4; ++j) w[j] = o1[g4 * 4 + j] * inv;
            *(f32x4*)(Out + orow + 32 + g4 * 8 + hi * 4) = w;
        }
    }
}

// ---------------- fallback (used only if ws too small) ----------------
__device__ __forceinline__ void load_tile_fb(const float* __restrict__ Kb,
                                             const float* __restrict__ Vb,
                                             int tid, f32x4 kv[4], f32x4 vv[4]) {
    #pragma unroll
    for (int h = 0; h < 4; ++h) {
        const int c = tid + h * 256;
        kv[h] = *(const f32x4*)(Kb + (c >> 4) * 64 + (c & 15) * 4);
    }
    #pragma unroll
    for (int h = 0; h < 2; ++h) {
        const int u  = tid + h * 256;
        const int d4 = (u & 3) + ((u >> 7) << 2);
        const int kp = (u >> 2) & 31;
        vv[2 * h]     = *(const f32x4*)(Vb + (2 * kp) * 64 + d4 * 4);
        vv[2 * h + 1] = *(const f32x4*)(Vb + (2 * kp + 1) * 64 + d4 * 4);
    }
}

__global__ __launch_bounds__(256, 4)
void attn_fb(const float* __restrict__ Qp, const float* __restrict__ Kp,
             const float* __restrict__ Vp, const int* __restrict__ meta,
             float* __restrict__ Out) {
    constexpr int S = SEQ;
    constexpr int qtiles = S >> 6;
    __shared__ short        lK [64 * KSTR];
    __shared__ unsigned int lVt[64 * VSTR];
    __shared__ unsigned int lPt[4 * 32 * PSTR];
    const int tid = threadIdx.x;
    const int wave = tid >> 6, lane = tid & 63;
    const int l15 = lane & 15, grp = lane >> 4;
    const int slot = blockIdx.x / qtiles, qt = blockIdx.x % qtiles;
    const int vl = meta[slot], batch = meta[BATCH + slot];
    const int ntiles = (vl + 63) >> 6;
    const float* Kb = Kp + (size_t)batch * S * 64;
    const float* Vb = Vp + (size_t)batch * S * 64;
    bf16x8 qf[2];
    {
        const float* qb = Qp + ((size_t)batch * S + qt * 64 + wave * 16 + l15) * 64 + grp * 8;
        #pragma unroll
        for (int kf = 0; kf < 2; ++kf) {
            f32x4 a = *(const f32x4*)(qb + kf * 32);
            f32x4 b = *(const f32x4*)(qb + kf * 32 + 4);
            union { bf16x8 v; unsigned int u[4]; } qq;
            qq.u[0] = pk2(a[0], a[1]); qq.u[1] = pk2(a[2], a[3]);
            qq.u[2] = pk2(b[0], b[1]); qq.u[3] = pk2(b[2], b[3]);
            qf[kf] = qq.v;
        }
    }
    f32x4 o[4] = {{0.f,0.f,0.f,0.f},{0.f,0.f,0.f,0.f},{0.f,0.f,0.f,0.f},{0.f,0.f,0.f,0.f}};
    float mrun = -INFINITY, lrun = 0.f;
    unsigned int* pw = &lPt[wave * 32 * PSTR];
    f32x4 kv[4], vv[4];
    if (ntiles > 0) load_tile_fb(Kb, Vb, tid, kv, vv);
    for (int kt = 0; kt < ntiles; ++kt) {
        const int kb = kt * 64;
        __syncthreads();
        #pragma unroll
        for (int h = 0; h < 4; ++h) {
            const int c = tid + h * 256;
            const int row = c >> 4, col = (c & 15) * 4;
            union { f32x4 f; float e[4]; } x; x.f = kv[h];
            unsigned int* dst = (unsigned int*)&lK[row * KSTR + col];
            dst[0] = pk2(x.e[0], x.e[1]); dst[1] = pk2(x.e[2], x.e[3]);
        }
        #pragma unroll
        for (int h = 0; h < 2; ++h) {
            const int u  = tid + h * 256;
            const int d4 = (u & 3) + ((u >> 7) << 2);
            const int kp = (u >> 2) & 31;
            union { f32x4 f; float e[4]; } a, b;
            a.f = vv[2 * h]; b.f = vv[2 * h + 1];
            #pragma unroll
            for (int j = 0; j < 4; ++j)
                lVt[(d4 * 4 + j) * VSTR + kp] = pk2(a.e[j], b.e[j]);
        }
        if (kt + 1 < ntiles) load_tile_fb(Kb + (size_t)(kb + 64) * 64, Vb + (size_t)(kb + 64) * 64, tid, kv, vv);
        __syncthreads();
        f32x4 st[4] = {{0.f,0.f,0.f,0.f},{0.f,0.f,0.f,0.f},{0.f,0.f,0.f,0.f},{0.f,0.f,0.f,0.f}};
        #pragma unroll
        for (int kf = 0; kf < 2; ++kf) {
            #pragma unroll
            for (int ct = 0; ct < 4; ++ct) {
                bf16x8 kfr = *(const bf16x8*)&lK[(ct * 16 + l15) * KSTR + kf * 32 + grp * 8];
                st[ct] = __builtin_amdgcn_mfma_f32_16x16x32_bf16(kfr, qf[kf], st[ct], 0, 0, 0);
            }
        }
        #pragma unroll
        for (int ct = 0; ct < 4; ++ct)
            #pragma unroll
            for (int r = 0; r < 4; ++r) {
                const bool valid = (kb + ct * 16 + grp * 4 + r) < vl;
                st[ct][r] = valid ? st[ct][r] * (0.125f * LOG2E) : NEGL;
            }
        float t0 = fmaxf(fmaxf(st[0][0], st[0][1]), fmaxf(st[0][2], st[0][3]));
        float t1 = fmaxf(fmaxf(st[1][0], st[1][1]), fmaxf(st[1][2], st[1][3]));
        float t2 = fmaxf(fmaxf(st[2][0], st[2][1]), fmaxf(st[2][2], st[2][3]));
        float t3 = fmaxf(fmaxf(st[3][0], st[3][1]), fmaxf(st[3][2], st[3][3]));
        float tm = fmaxf(fmaxf(t0, t1), fmaxf(t2, t3));
        tm = fmaxf(tm, __shfl_xor(tm, 16));
        tm = fmaxf(tm, __shfl_xor(tm, 32));
        const float mnew  = fmaxf(mrun, tm);
        const float alpha = exp2f(mrun - mnew);
        mrun = mnew;
        lrun *= alpha;
        #pragma unroll
        for (int dt = 0; dt < 4; ++dt)
            #pragma unroll
            for (int r = 0; r < 4; ++r) o[dt][r] *= alpha;
        float rs = 0.f;
        #pragma unroll
        for (int ct = 0; ct < 4; ++ct) {
            #pragma unroll
            for (int r = 0; r < 4; ++r) {
                st[ct][r] = exp2f(st[ct][r] - mrun);
                rs += st[ct][r];
            }
            #pragma unroll
            for (int a = 0; a < 2; ++a)
                pw[(ct * 8 + grp * 2 + a) * PSTR + l15] = pk2(st[ct][2 * a], st[ct][2 * a + 1]);
        }
        rs += __shfl_xor(rs, 16);
        rs += __shfl_xor(rs, 32);
        lrun += rs;
        asm volatile("s_waitcnt lgkmcnt(0)" ::: "memory");
        #pragma unroll
        for (int kk = 0; kk < 2; ++kk) {
            union { bf16x8 v; unsigned int u[4]; } pf;
            #pragma unroll
            for (int jj = 0; jj < 4; ++jj)
                pf.u[jj] = pw[(kk * 16 + grp * 4 + jj) * PSTR + l15];
            #pragma unroll
            for (int dt = 0; dt < 4; ++dt) {
                bf16x8 vf = *(const bf16x8*)&lVt[(dt * 16 + l15) * VSTR + kk * 16 + grp * 4];
                o[dt] = __builtin_amdgcn_mfma_f32_16x16x32_bf16(vf, pf.v, o[dt], 0, 0, 0);
            }
        }
    }
    const float inv = (lrun > 0.f) ? 1.0f / lrun : 0.f;
    const size_t orow = ((size_t)batch * S + qt * 64 + wave * 16 + l15) * 64;
    #pragma unroll
    for (int dt = 0; dt < 4; ++dt) {
        f32x4 w = o[dt];
        w[0] *= inv; w[1] *= inv; w[2] *= inv; w[3] *= inv;
        *(f32x4*)(Out + orow + dt * 16 + grp * 4) = w;
    }
}

extern "C" void kernel_launch(void* const* d_in, const int* in_sizes, int n_in,
                              void* d_out, int out_size, void* d_ws, size_t ws_size,
                              hipStream_t stream) {
    const float* Q  = (const float*)d_in[0];
    const float* K  = (const float*)d_in[1];
    const float* V  = (const float*)d_in[2];
    const int*   VL = (const int*)d_in[3];
    int* meta = (int*)d_ws;                    // 64 ints
    const size_t need = 512 + 2 * (size_t)BATCH * SEQ * 64 * sizeof(short);  // ~16.8 MB
    dim3 block(256);
    if (ws_size >= need) {
        short* Kb = (short*)((char*)d_ws + 512);
        short* Vt = Kb + (size_t)BATCH * SEQ * 64;
        prepkv<<<dim3(BATCH * 32 + 1), block, 0, stream>>>(K, V, VL, Kb, Vt, meta);
        attn_fwd<<<dim3(BATCH * 32), block, 0, stream>>>(Q, Kb, Vt, meta, (float*)d_out);
    } else {
        prep_vl<<<1, 64, 0, stream>>>(VL, meta);
        attn_fb<<<dim3(BATCH * (SEQ >> 6)), block, 0, stream>>>(Q, K, V, meta, (float*)d_out);
    }
}

// Round 5
// 125.917 us; speedup vs baseline: 2.2270x; 1.0026x over previous
//
#include <hip/hip_runtime.h>
#include <hip/hip_bf16.h>

typedef __attribute__((ext_vector_type(8))) short bf16x8;
typedef __attribute__((ext_vector_type(4))) float f32x4;
typedef __attribute__((ext_vector_type(16))) float f32x16;

#define BATCH 32
#define SEQ   2048
#define PSTR  20    // fallback kernel only
#define KSTR  72    // fallback kernel only
#define VSTR  36    // fallback + prepkv staging
#define LOG2E 1.44269504088896340736f
#define QSCALE (0.125f * LOG2E)
#define NEGL  (-1000000.0f * LOG2E)

__device__ __forceinline__ unsigned int pk2(float lo, float hi) {
    __hip_bfloat162 h2 = __float22bfloat162_rn(make_float2(lo, hi));  // v_cvt_pk_bf16_f32
    return *reinterpret_cast<unsigned int*>(&h2);
}

__device__ __forceinline__ void dma16(const short* g, short* l) {
    __builtin_amdgcn_global_load_lds((const __attribute__((address_space(1))) void*)g,
                                     (__attribute__((address_space(3))) void*)l, 16, 0, 0);
}

// v_permlane32_swap_b32: a[32:63] <-> b[0:31].
__device__ __forceinline__ void plswap(unsigned int& a, unsigned int& b) {
    asm volatile("v_permlane32_swap_b32 %0, %1" : "+v"(a), "+v"(b));
}

// standalone prep (fallback path only)
__global__ void prep_vl(const int* __restrict__ VL, int* __restrict__ meta) {
    __shared__ int sv[BATCH];
    const int t = threadIdx.x;
    int odd = (t < 16) ? VL[2 * t + 1] : 0;
    const bool is64 = (__ballot(odd != 0) == 0ULL);
    if (t < BATCH) {
        int x = is64 ? VL[2 * t] : VL[t];
        x = x < 0 ? 0 : (x > SEQ ? SEQ : x);
        sv[t] = x;
    }
    __syncthreads();
    if (t < BATCH) {
        const int x = sv[t];
        int rank = 0;
        for (int j = 0; j < BATCH; ++j) {
            const int y = sv[j];
            rank += (y > x) || (y == x && j < t);
        }
        meta[rank] = x;
        meta[BATCH + rank] = t;
    }
}

// K fp32->bf16 row-major [b][key][d]; V fp32->bf16 TILE-MAJOR transposed
// Vt[b][kt][d][64 keys] (packed key-pairs). Tiles entirely beyond vl[b] are
// SKIPPED (attn never stages them). Block BATCH*32 does the meta rank-sort.
__global__ __launch_bounds__(256) void prepkv(const float* __restrict__ Kp,
                                              const float* __restrict__ Vp,
                                              const int* __restrict__ VL,
                                              short* __restrict__ Kb,
                                              short* __restrict__ Vt,
                                              int* __restrict__ meta) {
    __shared__ unsigned int l[64 * VSTR];
    __shared__ int sv[BATCH];
    __shared__ int svl;
    const int tid = threadIdx.x;
    if (blockIdx.x == BATCH * 32) {
        if (tid < 64) {
            int odd = (tid < 16) ? VL[2 * tid + 1] : 0;
            const bool is64 = (__ballot(odd != 0) == 0ULL);   // lens>=1
            if (tid < BATCH) {
                int x = is64 ? VL[2 * tid] : VL[tid];
                x = x < 0 ? 0 : (x > SEQ ? SEQ : x);
                sv[tid] = x;
            }
            asm volatile("s_waitcnt lgkmcnt(0)" ::: "memory");
            if (tid < BATCH) {
                const int x = sv[tid];
                int rank = 0;
                for (int j = 0; j < BATCH; ++j) {
                    const int y = sv[j];
                    rank += (y > x) || (y == x && j < tid);
                }
                meta[rank] = x;
                meta[BATCH + rank] = tid;
            }
        }
        return;
    }
    const int b = blockIdx.x >> 5, kt = blockIdx.x & 31, kb = kt * 64;
    // per-block vl: skip tiles attn never reads (kt*64 >= vl)
    if (tid < 64) {
        int odd = (tid < 16) ? VL[2 * tid + 1] : 0;
        const bool is64 = (__ballot(odd != 0) == 0ULL);
        if (tid == 0) {
            int x = is64 ? VL[2 * b] : VL[b];
            x = x < 0 ? 0 : (x > SEQ ? SEQ : x);
            svl = x;
        }
    }
    __syncthreads();
    if (kb >= svl) return;   // block-uniform exit
    const float* Kv = Kp + ((size_t)b * SEQ + kb) * 64;
    const float* Vb = Vp + ((size_t)b * SEQ + kb) * 64;
    #pragma unroll
    for (int h = 0; h < 4; ++h) {
        const int c = tid + h * 256;
        const int row = c >> 4, col = (c & 15) * 4;
        f32x4 x = *(const f32x4*)(Kv + row * 64 + col);
        unsigned int* dst = (unsigned int*)(Kb + ((size_t)b * SEQ + kb + row) * 64 + col);
        dst[0] = pk2(x[0], x[1]); dst[1] = pk2(x[2], x[3]);
    }
    #pragma unroll
    for (int h = 0; h < 2; ++h) {
        const int u = tid + h * 256;
        const int d4 = (u & 3) + ((u >> 7) << 2);
        const int kp = (u >> 2) & 31;
        f32x4 a = *(const f32x4*)(Vb + (2 * kp) * 64 + d4 * 4);
        f32x4 c = *(const f32x4*)(Vb + (2 * kp + 1) * 64 + d4 * 4);
        #pragma unroll
        for (int j = 0; j < 4; ++j)
            l[(d4 * 4 + j) * VSTR + kp] = pk2(a[j], c[j]);
    }
    __syncthreads();
    // tile-major write: uint index ((b*32+kt)*64 + d)*32 + kp -> contiguous 8 KB/block
    const int d = tid >> 2, cg = tid & 3;
    unsigned int w[8];
    #pragma unroll
    for (int j = 0; j < 8; ++j) w[j] = l[d * VSTR + cg * 8 + j];
    unsigned int* dst = (unsigned int*)Vt + ((size_t)(b * 32 + kt) * 64 + d) * 32 + cg * 8;
    #pragma unroll
    for (int j = 0; j < 8; ++j) dst[j] = w[j];
}

// ---- main: round-15 = round-4 core + T15 one-stage software pipeline:
// PV(kt-1) issues right after QK(kt) (8 independent MFMAs in one setprio
// cluster), softmax(kt) VALU then overlaps the in-flight PV MFMAs. pf frags
// persist across the barrier (8 VGPR). V gets a 3-buffer ring (tile kt-1 must
// stay live while kt+1 stages): LDS 16K K + 24K V = 40 KB -> still 4 blk/CU.
// kh-skip guard dropped (rem-mask yields exp2->0 exactly; uniform control
// flow); epilogue runs the final PV after the loop. Round-4 post-mortem:
// VALU 46% top pipe, MFMA/VALU serialization was the stall -> overlap them. ----
__global__ __launch_bounds__(256, 4)
void attn_fwd(const float* __restrict__ Qp, const short* __restrict__ Kb,
              const short* __restrict__ Vt, const int* __restrict__ meta,
              float* __restrict__ Out) {
    constexpr int S = SEQ;
    __shared__ short bK2[2 * 4096];   // K double buffer (16 KB)
    __shared__ short bV3[3 * 4096];   // V ring (24 KB)

    const int tid  = threadIdx.x;
    const int wave = tid >> 6, lane = tid & 63;
    const int r31 = lane & 31, hi = lane >> 5;
    const int l7  = lane & 7;
    const int qh = wave >> 1, kh = wave & 1;   // q-half, key-half

    // snake remap: CU c gets slots {k,15-k,16+k,31-k} -> balanced tile sums
    const int g  = blockIdx.x >> 8;
    const int k8 = (blockIdx.x >> 5) & 7;
    const int qt = blockIdx.x & 31;
    const int slot = (g << 3) + ((g & 1) ? 7 - k8 : k8);

    const int vl = meta[slot], batch = meta[BATCH + slot];
    const int ntiles = (vl + 63) >> 6;

    const short* Kbb = Kb + (size_t)batch * S * 64;
    const short* Vtb = Vt + (size_t)batch * 32 * 4096;   // tile-major: 4096 shorts/tile

    // staging: source-side XOR swizzle (linear LDS dest + pre-swizzled global
    // source + swizzled read). LDS[row][slot s] = G[row][s ^ (row&7)].
    const int r8 = lane >> 3, s8 = lane & 7, csw = s8 ^ r8;
    const short* gK0 = Kbb + (wave * 16 + r8) * 64 + csw * 8;
    const short* gV0 = Vtb + (wave * 16 + r8) * 64 + csw * 8;
    short* lK0 = &bK2[wave * 16 * 64];
    short* lV0 = &bV3[wave * 16 * 64];

    // Q B-fragments: lane holds Q[qh*32+r31][kf*16+hi*8+j], scale folded
    // (scores exit MFMA in log2 domain)
    bf16x8 qf[4];
    {
        const float* qb = Qp + ((size_t)batch * S + qt * 64 + qh * 32 + r31) * 64 + hi * 8;
        #pragma unroll
        for (int kf = 0; kf < 4; ++kf) {
            f32x4 a = *(const f32x4*)(qb + kf * 16);
            f32x4 c = *(const f32x4*)(qb + kf * 16 + 4);
            union { bf16x8 v; unsigned int u[4]; } qq;
            qq.u[0] = pk2(a[0] * QSCALE, a[1] * QSCALE);
            qq.u[1] = pk2(a[2] * QSCALE, a[3] * QSCALE);
            qq.u[2] = pk2(c[0] * QSCALE, c[1] * QSCALE);
            qq.u[3] = pk2(c[2] * QSCALE, c[3] * QSCALE);
            qf[kf] = qq.v;
        }
    }

    f32x16 o0, o1, zv;
    #pragma unroll
    for (int r = 0; r < 16; ++r) { o0[r] = 0.f; o1[r] = 0.f; zv[r] = 0.f; }
    float lpart = 0.f;                      // per-lane partial Σp; merged ONCE at end
    const int krow = kh * 32 + r31;

    // V ring byte offsets for tiles (kt-1, kt, kt+1)
    int vP = 16384, vC = 0, vN = 8192;
    union { bf16x8 v; unsigned int u[4]; } pf0, pf1;   // pf(kt-1), persists across barrier

    if (ntiles > 0) {
        dma16(gK0,       lK0);
        dma16(gK0 + 512, lK0 + 512);
        dma16(gV0,       lV0);
        dma16(gV0 + 512, lV0 + 512);
    }

    for (int kt = 0; kt < ntiles; ++kt) {
        __syncthreads();   // publishes K(kt),V(kt); drains own DMA; frees ring slot vN
        if (kt + 1 < ntiles) {
            const int ko = (kt + 1) * 4096;
            short* ktgt = lK0 + (((kt + 1) & 1) << 12);
            short* vtgt = (short*)((char*)lV0 + vN);
            dma16(gK0 + ko,       ktgt);
            dma16(gK0 + ko + 512, ktgt + 512);
            dma16(gV0 + ko,       vtgt);
            dma16(gV0 + ko + 512, vtgt + 512);
        }

        const char* cK = (const char*)bK2 + ((kt & 1) << 13);
        f32x16 st;
        __builtin_amdgcn_s_setprio(1);
        {   // QK(kt): 4 MFMA
            bf16x8 k0 = *(const bf16x8*)(cK + krow * 128 + (((0 + hi) ^ l7) << 4));
            bf16x8 k1 = *(const bf16x8*)(cK + krow * 128 + (((2 + hi) ^ l7) << 4));
            bf16x8 k2 = *(const bf16x8*)(cK + krow * 128 + (((4 + hi) ^ l7) << 4));
            bf16x8 k3 = *(const bf16x8*)(cK + krow * 128 + (((6 + hi) ^ l7) << 4));
            st = __builtin_amdgcn_mfma_f32_32x32x16_bf16(k0, qf[0], zv, 0, 0, 0);
            st = __builtin_amdgcn_mfma_f32_32x32x16_bf16(k1, qf[1], st, 0, 0, 0);
            st = __builtin_amdgcn_mfma_f32_32x32x16_bf16(k2, qf[2], st, 0, 0, 0);
            st = __builtin_amdgcn_mfma_f32_32x32x16_bf16(k3, qf[3], st, 0, 0, 0);
        }
        if (kt > 0) {   // PV(kt-1): 4 independent MFMA, overlap softmax(kt) below
            const char* cV = (const char*)bV3 + vP;
            bf16x8 vf0 = *(const bf16x8*)(cV + r31 * 128 + (((kh * 4 + hi) ^ l7) << 4));
            o0 = __builtin_amdgcn_mfma_f32_32x32x16_bf16(vf0, pf0.v, o0, 0, 0, 0);
            bf16x8 vf1 = *(const bf16x8*)(cV + r31 * 128 + (((kh * 4 + 2 + hi) ^ l7) << 4));
            o0 = __builtin_amdgcn_mfma_f32_32x32x16_bf16(vf1, pf1.v, o0, 0, 0, 0);
            bf16x8 vf2 = *(const bf16x8*)(cV + (32 + r31) * 128 + (((kh * 4 + hi) ^ l7) << 4));
            o1 = __builtin_amdgcn_mfma_f32_32x32x16_bf16(vf2, pf0.v, o1, 0, 0, 0);
            bf16x8 vf3 = *(const bf16x8*)(cV + (32 + r31) * 128 + (((kh * 4 + 2 + hi) ^ l7) << 4));
            o1 = __builtin_amdgcn_mfma_f32_32x32x16_bf16(vf3, pf1.v, o1, 0, 0, 0);
        }
        __builtin_amdgcn_s_setprio(0);

        // mask tail (rem<=0 -> all masked -> pf=0; uniform branch)
        const int rem = vl - (kt * 64 + kh * 32);
        if (rem < 32) {
            #pragma unroll
            for (int r = 0; r < 16; ++r) {
                const int kl = 4 * hi + (r & 3) + 8 * (r >> 2);
                st[r] = (kl < rem) ? st[r] : NEGL;
            }
        }

        // p = exp2(s') (log2 domain, no max subtraction; masked -> exactly 0)
        #pragma unroll
        for (int r = 0; r < 16; ++r) st[r] = exp2f(st[r]);
        {
            const float a0 = (st[0] + st[1]) + (st[2] + st[3]);
            const float a1 = (st[4] + st[5]) + (st[6] + st[7]);
            const float a2 = (st[8] + st[9]) + (st[10] + st[11]);
            const float a3 = (st[12] + st[13]) + (st[14] + st[15]);
            lpart += (a0 + a1) + (a2 + a3);
        }

        // in-register P^T -> PV B-fragments (T12); consumed NEXT iteration
        {
            unsigned int x0 = pk2(st[0], st[1]),   y0 = pk2(st[4], st[5]);
            unsigned int x1 = pk2(st[2], st[3]),   y1 = pk2(st[6], st[7]);
            plswap(x0, y0); plswap(x1, y1);
            pf0.u[0] = x0; pf0.u[1] = x1; pf0.u[2] = y0; pf0.u[3] = y1;
            unsigned int x2 = pk2(st[8], st[9]),   y2 = pk2(st[12], st[13]);
            unsigned int x3 = pk2(st[10], st[11]), y3 = pk2(st[14], st[15]);
            plswap(x2, y2); plswap(x3, y3);
            pf1.u[0] = x2; pf1.u[1] = x3; pf1.u[2] = y2; pf1.u[3] = y3;
        }

        // rotate V ring
        const int t_ = vP; vP = vC; vC = vN; vN = t_;
    }

    // epilogue: PV(ntiles-1) — ring slot vP still live (no DMA overwrote it)
    {
        const char* cV = (const char*)bV3 + vP;
        __builtin_amdgcn_s_setprio(1);
        bf16x8 vf0 = *(const bf16x8*)(cV + r31 * 128 + (((kh * 4 + hi) ^ l7) << 4));
        o0 = __builtin_amdgcn_mfma_f32_32x32x16_bf16(vf0, pf0.v, o0, 0, 0, 0);
        bf16x8 vf1 = *(const bf16x8*)(cV + r31 * 128 + (((kh * 4 + 2 + hi) ^ l7) << 4));
        o0 = __builtin_amdgcn_mfma_f32_32x32x16_bf16(vf1, pf1.v, o0, 0, 0, 0);
        bf16x8 vf2 = *(const bf16x8*)(cV + (32 + r31) * 128 + (((kh * 4 + hi) ^ l7) << 4));
        o1 = __builtin_amdgcn_mfma_f32_32x32x16_bf16(vf2, pf0.v, o1, 0, 0, 0);
        bf16x8 vf3 = *(const bf16x8*)(cV + (32 + r31) * 128 + (((kh * 4 + 2 + hi) ^ l7) << 4));
        o1 = __builtin_amdgcn_mfma_f32_32x32x16_bf16(vf3, pf1.v, o1, 0, 0, 0);
        __builtin_amdgcn_s_setprio(0);
    }

    // per-(q, key-half) l: lanes l and l+32 hold complementary row sets
    float lw = lpart + __shfl_xor(lpart, 32);

    // cross-wave merge (kh=0 += kh=1): pure sums, once per block
    __syncthreads();                          // all waves done reading K/V tiles
    float* mrg = (float*)bK2;                 // 4096 floats = 16 KB (exact fit)
    float* lm  = (float*)bV3;
    if (kh == 1) {
        #pragma unroll
        for (int r = 0; r < 16; ++r) mrg[qh * 2048 + r * 64 + lane] = o0[r];
        #pragma unroll
        for (int r = 0; r < 16; ++r) mrg[qh * 2048 + (16 + r) * 64 + lane] = o1[r];
        lm[qh * 64 + lane] = lw;
    }
    __syncthreads();
    if (kh == 0) {
        #pragma unroll
        for (int r = 0; r < 16; ++r) o0[r] += mrg[qh * 2048 + r * 64 + lane];
        #pragma unroll
        for (int r = 0; r < 16; ++r) o1[r] += mrg[qh * 2048 + (16 + r) * 64 + lane];
        lw += lm[qh * 64 + lane];
        const float inv = (lw > 0.f) ? 1.0f / lw : 0.f;
        const size_t orow = ((size_t)batch * S + qt * 64 + qh * 32 + r31) * 64;
        #pragma unroll
        for (int g4 = 0; g4 < 4; ++g4) {
            f32x4 w;
            #pragma unroll
            for (int j = 0; j < 4; ++j) w[j] = o0[g4 * 4 + j] * inv;
            *(f32x4*)(Out + orow + g4 * 8 + hi * 4) = w;
        }
        #pragma unroll
        for (int g4 = 0; g4 < 4; ++g4) {
            f32x4 w;
            #pragma unroll
            for (int j = 0; j < 4; ++j) w[j] = o1[g4 * 4 + j] * inv;
            *(f32x4*)(Out + orow + 32 + g4 * 8 + hi * 4) = w;
        }
    }
}

// ---------------- fallback (used only if ws too small) ----------------
__device__ __forceinline__ void load_tile_fb(const float* __restrict__ Kb,
                                             const float* __restrict__ Vb,
                                             int tid, f32x4 kv[4], f32x4 vv[4]) {
    #pragma unroll
    for (int h = 0; h < 4; ++h) {
        const int c = tid + h * 256;
        kv[h] = *(const f32x4*)(Kb + (c >> 4) * 64 + (c & 15) * 4);
    }
    #pragma unroll
    for (int h = 0; h < 2; ++h) {
        const int u  = tid + h * 256;
        const int d4 = (u & 3) + ((u >> 7) << 2);
        const int kp = (u >> 2) & 31;
        vv[2 * h]     = *(const f32x4*)(Vb + (2 * kp) * 64 + d4 * 4);
        vv[2 * h + 1] = *(const f32x4*)(Vb + (2 * kp + 1) * 64 + d4 * 4);
    }
}

__global__ __launch_bounds__(256, 4)
void attn_fb(const float* __restrict__ Qp, const float* __restrict__ Kp,
             const float* __restrict__ Vp, const int* __restrict__ meta,
             float* __restrict__ Out) {
    constexpr int S = SEQ;
    constexpr int qtiles = S >> 6;
    __shared__ short        lK [64 * KSTR];
    __shared__ unsigned int lVt[64 * VSTR];
    __shared__ unsigned int lPt[4 * 32 * PSTR];
    const int tid = threadIdx.x;
    const int wave = tid >> 6, lane = tid & 63;
    const int l15 = lane & 15, grp = lane >> 4;
    const int slot = blockIdx.x / qtiles, qt = blockIdx.x % qtiles;
    const int vl = meta[slot], batch = meta[BATCH + slot];
    const int ntiles = (vl + 63) >> 6;
    const float* Kb = Kp + (size_t)batch * S * 64;
    const float* Vb = Vp + (size_t)batch * S * 64;
    bf16x8 qf[2];
    {
        const float* qb = Qp + ((size_t)batch * S + qt * 64 + wave * 16 + l15) * 64 + grp * 8;
        #pragma unroll
        for (int kf = 0; kf < 2; ++kf) {
            f32x4 a = *(const f32x4*)(qb + kf * 32);
            f32x4 b = *(const f32x4*)(qb + kf * 32 + 4);
            union { bf16x8 v; unsigned int u[4]; } qq;
            qq.u[0] = pk2(a[0], a[1]); qq.u[1] = pk2(a[2], a[3]);
            qq.u[2] = pk2(b[0], b[1]); qq.u[3] = pk2(b[2], b[3]);
            qf[kf] = qq.v;
        }
    }
    f32x4 o[4] = {{0.f,0.f,0.f,0.f},{0.f,0.f,0.f,0.f},{0.f,0.f,0.f,0.f},{0.f,0.f,0.f,0.f}};
    float mrun = -INFINITY, lrun = 0.f;
    unsigned int* pw = &lPt[wave * 32 * PSTR];
    f32x4 kv[4], vv[4];
    if (ntiles > 0) load_tile_fb(Kb, Vb, tid, kv, vv);
    for (int kt = 0; kt < ntiles; ++kt) {
        const int kb = kt * 64;
        __syncthreads();
        #pragma unroll
        for (int h = 0; h < 4; ++h) {
            const int c = tid + h * 256;
            const int row = c >> 4, col = (c & 15) * 4;
            union { f32x4 f; float e[4]; } x; x.f = kv[h];
            unsigned int* dst = (unsigned int*)&lK[row * KSTR + col];
            dst[0] = pk2(x.e[0], x.e[1]); dst[1] = pk2(x.e[2], x.e[3]);
        }
        #pragma unroll
        for (int h = 0; h < 2; ++h) {
            const int u  = tid + h * 256;
            const int d4 = (u & 3) + ((u >> 7) << 2);
            const int kp = (u >> 2) & 31;
            union { f32x4 f; float e[4]; } a, b;
            a.f = vv[2 * h]; b.f = vv[2 * h + 1];
            #pragma unroll
            for (int j = 0; j < 4; ++j)
                lVt[(d4 * 4 + j) * VSTR + kp] = pk2(a.e[j], b.e[j]);
        }
        if (kt + 1 < ntiles) load_tile_fb(Kb + (size_t)(kb + 64) * 64, Vb + (size_t)(kb + 64) * 64, tid, kv, vv);
        __syncthreads();
        f32x4 st[4] = {{0.f,0.f,0.f,0.f},{0.f,0.f,0.f,0.f},{0.f,0.f,0.f,0.f},{0.f,0.f,0.f,0.f}};
        #pragma unroll
        for (int kf = 0; kf < 2; ++kf) {
            #pragma unroll
            for (int ct = 0; ct < 4; ++ct) {
                bf16x8 kfr = *(const bf16x8*)&lK[(ct * 16 + l15) * KSTR + kf * 32 + grp * 8];
                st[ct] = __builtin_amdgcn_mfma_f32_16x16x32_bf16(kfr, qf[kf], st[ct], 0, 0, 0);
            }
        }
        #pragma unroll
        for (int ct = 0; ct < 4; ++ct)
            #pragma unroll
            for (int r = 0; r < 4; ++r) {
                const bool valid = (kb + ct * 16 + grp * 4 + r) < vl;
                st[ct][r] = valid ? st[ct][r] * (0.125f * LOG2E) : NEGL;
            }
        float t0 = fmaxf(fmaxf(st[0][0], st[0][1]), fmaxf(st[0][2], st[0][3]));
        float t1 = fmaxf(fmaxf(st[1][0], st[1][1]), fmaxf(st[1][2], st[1][3]));
        float t2 = fmaxf(fmaxf(st[2][0], st[2][1]), fmaxf(st[2][2], st[2][3]));
        float t3 = fmaxf(fmaxf(st[3][0], st[3][1]), fmaxf(st[3][2], st[3][3]));
        float tm = fmaxf(fmaxf(t0, t1), fmaxf(t2, t3));
        tm = fmaxf(tm, __shfl_xor(tm, 16));
        tm = fmaxf(tm, __shfl_xor(tm, 32));
        const float mnew  = fmaxf(mrun, tm);
        const float alpha = exp2f(mrun - mnew);
        mrun = mnew;
        lrun *= alpha;
        #pragma unroll
        for (int dt = 0; dt < 4; ++dt)
            #pragma unroll
            for (int r = 0; r < 4; ++r) o[dt][r] *= alpha;
        float rs = 0.f;
        #pragma unroll
        for (int ct = 0; ct < 4; ++ct) {
            #pragma unroll
            for (int r = 0; r < 4; ++r) {
                st[ct][r] = exp2f(st[ct][r] - mrun);
                rs += st[ct][r];
            }
            #pragma unroll
            for (int a = 0; a < 2; ++a)
                pw[(ct * 8 + grp * 2 + a) * PSTR + l15] = pk2(st[ct][2 * a], st[ct][2 * a + 1]);
        }
        rs += __shfl_xor(rs, 16);
        rs += __shfl_xor(rs, 32);
        lrun += rs;
        asm volatile("s_waitcnt lgkmcnt(0)" ::: "memory");
        #pragma unroll
        for (int kk = 0; kk < 2; ++kk) {
            union { bf16x8 v; unsigned int u[4]; } pf;
            #pragma unroll
            for (int jj = 0; jj < 4; ++jj)
                pf.u[jj] = pw[(kk * 16 + grp * 4 + jj) * PSTR + l15];
            #pragma unroll
            for (int dt = 0; dt < 4; ++dt) {
                bf16x8 vf = *(const bf16x8*)&lVt[(dt * 16 + l15) * VSTR + kk * 16 + grp * 4];
                o[dt] = __builtin_amdgcn_mfma_f32_16x16x32_bf16(vf, pf.v, o[dt], 0, 0, 0);
            }
        }
    }
    const float inv = (lrun > 0.f) ? 1.0f / lrun : 0.f;
    const size_t orow = ((size_t)batch * S + qt * 64 + wave * 16 + l15) * 64;
    #pragma unroll
    for (int dt = 0; dt < 4; ++dt) {
        f32x4 w = o[dt];
        w[0] *= inv; w[1] *= inv; w[2] *= inv; w[3] *= inv;
        *(f32x4*)(Out + orow + dt * 16 + grp * 4) = w;
    }
}

extern "C" void kernel_launch(void* const* d_in, const int* in_sizes, int n_in,
                              void* d_out, int out_size, void* d_ws, size_t ws_size,
                              hipStream_t stream) {
    const float* Q  = (const float*)d_in[0];
    const float* K  = (const float*)d_in[1];
    const float* V  = (const float*)d_in[2];
    const int*   VL = (const int*)d_in[3];
    int* meta = (int*)d_ws;                    // 64 ints
    const size_t need = 512 + 2 * (size_t)BATCH * SEQ * 64 * sizeof(short);  // ~16.8 MB
    dim3 block(256);
    if (ws_size >= need) {
        short* Kb = (short*)((char*)d_ws + 512);
        short* Vt = Kb + (size_t)BATCH * SEQ * 64;
        prepkv<<<dim3(BATCH * 32 + 1), block, 0, stream>>>(K, V, VL, Kb, Vt, meta);
        attn_fwd<<<dim3(BATCH * 32), block, 0, stream>>>(Q, Kb, Vt, meta, (float*)d_out);
    } else {
        prep_vl<<<1, 64, 0, stream>>>(VL, meta);
        attn_fb<<<dim3(BATCH * (SEQ >> 6)), block, 0, stream>>>(Q, K, V, meta, (float*)d_out);
    }
}